// Round 11
// baseline (2084.792 us; speedup 1.0000x reference)
//
#include <hip/hip_runtime.h>
#include <hip/hip_bf16.h>

typedef unsigned short ushort_t;
typedef short v8s __attribute__((ext_vector_type(8)));
typedef unsigned short v8u __attribute__((ext_vector_type(8)));
typedef unsigned short v4u __attribute__((ext_vector_type(4)));
typedef float v4f __attribute__((ext_vector_type(4)));

#define N_NODES 50000
#define N_EDGES 100000
#define N_GRAPH 2000
#define DIM     300
#define DIM2    600
#define NLAYER  5
#define NTASK   10
#define D4      75   // DIM/4
#define D4P     80   // padded chunk count for split-A planes (K-pad to 320)

// BATCHED over both GNNs: row space [0,NPAD) = graph0, [NPAD,2*NPAD) = graph1.
// fp32 node buffers (h2): row-major, LDA=304 (1216 B rows), 2*NPAD rows.
// bf16 MFMA operands (gather planes, y, weights): global memory in the GEMM's
// LDS tile layout [mt][ks][kb4][m128][j8]. R11: BOTH A and B fragments are read
// DIRECTLY from global to registers (contiguous 16 B/lane, L2/L3-hot) — the
// K-loop has NO LDS and NO barriers, so there is no per-step vmcnt drain and
// waves freely desynchronize to hide L2 latency (m114 wave-overlap mechanism).
#define LDA  304
#define NPAD 50048   // MT_TILES*128
#define KST1 10      // GEMM1 K-steps (K=320)
#define KST2 19      // GEMM2 K-steps (K=608) = y's blocked factor

#define KB1 40
#define NT1 5
#define KB2 76
#define NT2 3
#define MT_TILES 391    // ceil(50000/128) per graph
#define MT2      782    // both graphs

static __device__ __forceinline__ ushort_t f2bf(float f) {
    unsigned int u;
    __builtin_memcpy(&u, &f, 4);
    unsigned int lsb = (u >> 16) & 1u;
    u += 0x7fffu + lsb;
    return (ushort_t)(u >> 16);
}
// split fp32 into truncated-hi bf16 + residual bf16 (hi + lo ~= f to ~2^-17)
static __device__ __forceinline__ void split2(float f, ushort_t& h, ushort_t& l) {
    unsigned int u;
    __builtin_memcpy(&u, &f, 4);
    h = (ushort_t)(u >> 16);
    unsigned int um = u & 0xFFFF0000u;
    float hf;
    __builtin_memcpy(&hf, &um, 4);
    float lf = f - hf;
    unsigned int ul;
    __builtin_memcpy(&ul, &lf, 4);
    l = (ushort_t)(ul >> 16);
}

// bijective XCD-grouping swizzle (m204)
static __device__ __forceinline__ int swz_wgid(int orig, int nwg) {
    int xcd = orig & 7;
    int seq = orig >> 3;
    int q = nwg >> 3, r = nwg & 7;
    int base = (xcd < r) ? xcd * (q + 1) : r * (q + 1) + (xcd - r) * q;
    return base + seq;
}

// ---------------- CSR build (once per launch) ----------------
__global__ void k_deg(const int* __restrict__ ei, int* __restrict__ deg) {
    int e = blockIdx.x * blockDim.x + threadIdx.x;
    if (e >= N_EDGES) return;
    atomicAdd(&deg[ei[N_EDGES + e]], 1);
}

__global__ void k_scan1(const int* __restrict__ deg, int* __restrict__ excl,
                        int* __restrict__ blksum) {
    __shared__ int s[256];
    int i = blockIdx.x * 256 + threadIdx.x;
    int v = (i < N_NODES) ? deg[i] : 0;
    s[threadIdx.x] = v;
    __syncthreads();
#pragma unroll
    for (int o = 1; o < 256; o <<= 1) {
        int t = (threadIdx.x >= o) ? s[threadIdx.x - o] : 0;
        __syncthreads();
        s[threadIdx.x] += t;
        __syncthreads();
    }
    if (i < N_NODES) excl[i] = s[threadIdx.x] - v;
    if (threadIdx.x == 255) blksum[blockIdx.x] = s[255];
}

__global__ void k_scan2(int* __restrict__ blksum, int* __restrict__ blkoff, int nblk) {
    __shared__ int s[256];
    int v = (threadIdx.x < nblk) ? blksum[threadIdx.x] : 0;
    s[threadIdx.x] = v;
    __syncthreads();
#pragma unroll
    for (int o = 1; o < 256; o <<= 1) {
        int t = (threadIdx.x >= o) ? s[threadIdx.x - o] : 0;
        __syncthreads();
        s[threadIdx.x] += t;
        __syncthreads();
    }
    if (threadIdx.x < nblk) blkoff[threadIdx.x] = s[threadIdx.x] - v;
}

__global__ void k_scan3(const int* __restrict__ excl, const int* __restrict__ blkoff,
                        int* __restrict__ rowptr, int* __restrict__ fillptr) {
    int i = blockIdx.x * blockDim.x + threadIdx.x;
    if (i > N_NODES) return;
    int v = (i < N_NODES) ? (excl[i] + blkoff[i >> 8]) : N_EDGES;
    rowptr[i] = v;
    if (i < N_NODES) fillptr[i] = v;
}

__global__ void k_fill(const int* __restrict__ ei, const int* __restrict__ ea,
                       int* __restrict__ fillptr,
                       int* __restrict__ csrc, int* __restrict__ cea) {
    int e = blockIdx.x * blockDim.x + threadIdx.x;
    if (e >= N_EDGES) return;
    int dst = ei[N_EDGES + e];
    int pos = atomicAdd(&fillptr[dst], 1);
    csrc[pos] = ei[e];
    cea[pos] = (ea[2 * e + 0] << 16) | ea[2 * e + 1];
}

// BATCHED gather over both graphs. Grid is XCD-swizzled: consecutive node
// blocks stay on one XCD so the 64 B lines of the blocked plane output (8
// consecutive nodes per line) are assembled in a single L2 instead of being
// partially dirtied across XCDs (R10: 209 MB written vs 128 MB ideal).
// EMB (layer 0): h computed inline from xemb tables (L2-resident).
// !EMB: BN(+ReLU) of previous layer applied on the fly.
template <bool EMB>
__global__ void k_gather_agg(const int* __restrict__ rowptr0,
                             const int* __restrict__ csrc0,
                             const int* __restrict__ cea0,
                             const int* __restrict__ rowptr1,
                             const int* __restrict__ csrc1,
                             const int* __restrict__ cea1,
                             const int* __restrict__ x0,
                             const int* __restrict__ x1,
                             const float* __restrict__ xe1,
                             const float* __restrict__ xe2,
                             const float* __restrict__ hin,
                             const float* __restrict__ ee1,
                             const float* __restrict__ ee2,
                             const float* __restrict__ ee1sl,
                             const float* __restrict__ ee2sl,
                             const float* __restrict__ bnmean,
                             const float* __restrict__ bnrstd,
                             const float* __restrict__ bngam,
                             const float* __restrict__ bnbet,
                             ushort_t* __restrict__ aghi,
                             ushort_t* __restrict__ aglo,
                             int nwg) {
    int wgid = swz_wgid(blockIdx.x, nwg);
    int tid = wgid * blockDim.x + threadIdx.x;
    if (tid >= 2 * N_NODES * D4P) return;
    int gi = tid / D4P;
    int c = tid % D4P;
    int graph = (gi >= N_NODES) ? 1 : 0;
    int ln = gi - graph * N_NODES;          // local node id
    int row = graph * NPAD + ln;            // batched buffer row
    int d0 = c * 4;
    const int mt = row >> 7, m = row & 127;
    const int ks = d0 >> 5, kb = (d0 >> 3) & 3, jq = d0 & 7;
    const size_t off = (((size_t)mt * KST1 + ks) * 4 + kb) * 1024 + m * 8 + jq;
    if (c >= D4) {  // K-pad cols 300..319 -> exact zeros
        v4u z = (v4u){0, 0, 0, 0};
        *(v4u*)(aghi + off) = z;
        *(v4u*)(aglo + off) = z;
        return;
    }
    const int* rowptr = graph ? rowptr1 : rowptr0;
    const int* csrc   = graph ? csrc1   : csrc0;
    const int* cea    = graph ? cea1    : cea0;
    const int* xp     = graph ? x1      : x0;

    float4 m4, r4, g4, b4;
    if (!EMB) {
        const int bo = graph * DIM + d0;
        m4 = *(const float4*)(bnmean + bo);
        r4 = *(const float4*)(bnrstd + bo);
        g4 = *(const float4*)(bngam + d0);
        b4 = *(const float4*)(bnbet + d0);
    }
    auto hval = [&](int node) -> float4 {
        if (EMB) {
            int i0 = xp[node * 2 + 0];
            int i1 = xp[node * 2 + 1];
            float4 a = *(const float4*)(xe1 + (size_t)i0 * DIM + d0);
            float4 b = *(const float4*)(xe2 + (size_t)i1 * DIM + d0);
            float4 o;
            o.x = a.x + b.x; o.y = a.y + b.y; o.z = a.z + b.z; o.w = a.w + b.w;
            return o;
        } else {
            float4 v = *(const float4*)(hin + (size_t)(graph * NPAD + node) * LDA + d0);
            v.x = fmaxf((v.x - m4.x) * r4.x * g4.x + b4.x, 0.f);
            v.y = fmaxf((v.y - m4.y) * r4.y * g4.y + b4.y, 0.f);
            v.z = fmaxf((v.z - m4.z) * r4.z * g4.z + b4.z, 0.f);
            v.w = fmaxf((v.w - m4.w) * r4.w * g4.w + b4.w, 0.f);
            return v;
        }
    };
    float4 a = hval(ln);
    float4 e1 = *(const float4*)(ee1sl + d0);
    float4 e2 = *(const float4*)(ee2sl + d0);
    a.x += e1.x + e2.x; a.y += e1.y + e2.y; a.z += e1.z + e2.z; a.w += e1.w + e2.w;
    int p0 = rowptr[ln], p1 = rowptr[ln + 1];
    for (int p = p0; p < p1; ++p) {
        int src = csrc[p];
        int pk = cea[p];
        int a0 = pk >> 16, a1 = pk & 0xFFFF;
        float4 hv = hval(src);
        float4 f1 = *(const float4*)(ee1 + (size_t)a0 * DIM + d0);
        float4 f2 = *(const float4*)(ee2 + (size_t)a1 * DIM + d0);
        a.x += hv.x + f1.x + f2.x;
        a.y += hv.y + f1.y + f2.y;
        a.z += hv.z + f1.z + f2.z;
        a.w += hv.w + f1.w + f2.w;
    }
    float av[4] = {a.x, a.y, a.z, a.w};
    v4u hh, ll;
#pragma unroll
    for (int i = 0; i < 4; ++i) {
        ushort_t uh, ul;
        split2(av[i], uh, ul);
        hh[i] = uh;
        ll[i] = ul;
    }
    *(v4u*)(aghi + off) = hh;
    *(v4u*)(aglo + off) = ll;
}

// Pack weights W [L][K][N] fp32 -> hi/lo bf16 planes, layout [l][nt][kb][n(128)][j(8)]
__global__ void k_pack_w(const float* __restrict__ W,
                         ushort_t* __restrict__ hi,
                         ushort_t* __restrict__ lo,
                         int K, int N, int KBv, int NTv, int total) {
    int idx = blockIdx.x * blockDim.x + threadIdx.x;
    if (idx >= total) return;
    int j = idx & 7;
    int n = (idx >> 3) & 127;
    int tmp = idx >> 10;
    int kb = tmp % KBv; tmp /= KBv;
    int nt = tmp % NTv;
    int l = tmp / NTv;
    int k = kb * 8 + j;
    int ng = nt * 128 + n;
    float v = 0.f;
    if (k < K && ng < N) v = W[((size_t)l * K + k) * N + ng];
    ushort_t h, lw;
    split2(v, h, lw);
    hi[idx] = h;
    lo[idx] = lw;
}

// MFMA split-precision GEMM, BATCHED, BARRIER-FREE K-loop.
// A and B fragments both read directly from global (contiguous 16 B/lane;
// A streams once per block, B is L2-resident and reused across blocks).
// No LDS in the K-loop -> no per-step vmcnt drain, no wave lockstep; the
// compiler software-pipelines loads across K-steps and co-resident waves
// hide each other's L2 latency. MFMA order per accumulator identical to R10
// (hi*bh, hi*bl, lo*bh per ks) -> bit-identical numerics.
// BNSTAT: per-graph per-column sum/sumsq fused into the epilogue (2 KB LDS).
template <bool RELU, bool SPLITA, bool BNSTAT, typename OT>
__global__ __launch_bounds__(256) void k_gemm_mfma(
        const ushort_t* __restrict__ Ahi,
        const ushort_t* __restrict__ Alo,
        const ushort_t* __restrict__ Bhi,
        const ushort_t* __restrict__ Blo,
        const float* __restrict__ bias,
        OT* __restrict__ C,
        double* __restrict__ bnsum,
        double* __restrict__ bnsq,
        int M, int N, int Ksteps, int KBv, int NTv, int nwg,
        int ldc, int ncap, int ksout, int mtHalf) {
    __shared__ float sred[512];

    const int wgid = swz_wgid(blockIdx.x, nwg);
    const int nt = wgid % NTv;
    const int mt = wgid / NTv;
    const int t = threadIdx.x;

    const int w = t >> 6;
    const int lane = t & 63;
    const int wm = w >> 1;
    const int wn = w & 1;
    const int quad = lane >> 4;
    const int lr = lane & 15;

    v4f acc[4][4];
#pragma unroll
    for (int i = 0; i < 4; ++i)
#pragma unroll
        for (int j = 0; j < 4; ++j) acc[i][j] = (v4f){0.f, 0.f, 0.f, 0.f};

    const int aoff = quad * 1024 + (wm * 64 + lr) * 8;     // +s*128 per si
    const int boff = (wn * 64 + lr) * 8;                   // +sj*128 per sj

    for (int ks = 0; ks < Ksteps; ++ks) {
        const ushort_t* ah = Ahi + ((size_t)mt * Ksteps + ks) * 4096 + aoff;
        const ushort_t* al = SPLITA ? (Alo + ((size_t)mt * Ksteps + ks) * 4096 + aoff) : nullptr;
        const ushort_t* bh_p = Bhi + ((size_t)(nt * KBv + ks * 4 + quad)) * 1024 + boff;
        const ushort_t* bl_p = Blo + ((size_t)(nt * KBv + ks * 4 + quad)) * 1024 + boff;
        v8s a_hi[4], a_lo[4], b_hi[4], b_lo[4];
#pragma unroll
        for (int s = 0; s < 4; ++s) {
            a_hi[s] = *(const v8s*)(ah + s * 128);
            if (SPLITA) a_lo[s] = *(const v8s*)(al + s * 128);
            b_hi[s] = *(const v8s*)(bh_p + s * 128);
            b_lo[s] = *(const v8s*)(bl_p + s * 128);
        }
#pragma unroll
        for (int sj = 0; sj < 4; ++sj) {
#pragma unroll
            for (int si = 0; si < 4; ++si) {
                acc[si][sj] = __builtin_amdgcn_mfma_f32_16x16x32_bf16(
                    a_hi[si], b_hi[sj], acc[si][sj], 0, 0, 0);
                acc[si][sj] = __builtin_amdgcn_mfma_f32_16x16x32_bf16(
                    a_hi[si], b_lo[sj], acc[si][sj], 0, 0, 0);
                if (SPLITA)
                    acc[si][sj] = __builtin_amdgcn_mfma_f32_16x16x32_bf16(
                        a_lo[si], b_hi[sj], acc[si][sj], 0, 0, 0);
            }
        }
    }

    const int graph = (mt >= mtHalf) ? 1 : 0;
    float bsum[4], bsq[4];
    if (BNSTAT) {
#pragma unroll
        for (int sj = 0; sj < 4; ++sj) { bsum[sj] = 0.f; bsq[sj] = 0.f; }
    }
#pragma unroll
    for (int sj = 0; sj < 4; ++sj) {
        int col = nt * 128 + wn * 64 + sj * 16 + lr;
        if (col >= ncap) continue;
        float bv = (col < N) ? bias[col] : 0.f;   // pad cols -> exact 0
        size_t yb = 0;
        if (sizeof(OT) == 2)
            yb = (((size_t)mt * ksout + (col >> 5)) * 4 + ((col >> 3) & 3)) * 1024 + (col & 7);
#pragma unroll
        for (int si = 0; si < 4; ++si) {
#pragma unroll
            for (int r = 0; r < 4; ++r) {
                int m = wm * 64 + si * 16 + quad * 4 + r;
                size_t row = (size_t)mt * 128 + m;
                float v = acc[si][sj][r] + bv;
                if (RELU) v = fmaxf(v, 0.f);
                if (BNSTAT) {
                    int lrow = (mt - graph * mtHalf) * 128 + m;   // per-graph row
                    if (lrow < M) { bsum[sj] += v; bsq[sj] += v * v; }
                }
                if (sizeof(OT) == 2)
                    ((ushort_t*)C)[yb + m * 8] = f2bf(v);
                else
                    ((float*)C)[row * ldc + col] = v;
            }
        }
    }
    if (BNSTAT) {
#pragma unroll
        for (int sj = 0; sj < 4; ++sj) {
            bsum[sj] += __shfl_xor(bsum[sj], 16);
            bsum[sj] += __shfl_xor(bsum[sj], 32);
            bsq[sj]  += __shfl_xor(bsq[sj], 16);
            bsq[sj]  += __shfl_xor(bsq[sj], 32);
        }
        if (quad == 0) {
#pragma unroll
            for (int sj = 0; sj < 4; ++sj) {
                int idx = wm * 128 + wn * 64 + sj * 16 + lr;
                sred[idx] = bsum[sj];
                sred[256 + idx] = bsq[sj];
            }
        }
        __syncthreads();
        if (t < 128) {
            float s = sred[t] + sred[128 + t];
            float q = sred[256 + t] + sred[256 + 128 + t];
            int col = nt * 128 + t;
            if (col < N) {
                atomicAdd(&bnsum[graph * N + col], (double)s);
                atomicAdd(&bnsq[graph * N + col], (double)q);
            }
        }
    }
}

// finalize BN stats for BOTH graphs (2*DIM cols) AND zero accumulators
__global__ void k_bn_finalize(double* __restrict__ sum,
                              double* __restrict__ sumsq,
                              float* __restrict__ mean,
                              float* __restrict__ rstd) {
    int d = blockIdx.x * blockDim.x + threadIdx.x;
    if (d >= 2 * DIM) return;
    double mu = sum[d] / (double)N_NODES;
    double var = sumsq[d] / (double)N_NODES - mu * mu;
    if (var < 0.0) var = 0.0;
    mean[d] = (float)mu;
    rstd[d] = (float)(1.0 / sqrt(var + 1e-5));
    sum[d] = 0.0;
    sumsq[d] = 0.0;
}

// Final layer, BATCHED: fused BN (no relu) + out_node write + segmented mean pool.
__global__ __launch_bounds__(256) void k_bn_pool(const float* __restrict__ h2,
                                                 const int* __restrict__ bat0,
                                                 const int* __restrict__ bat1,
                                                 const float* __restrict__ mean,
                                                 const float* __restrict__ rstd,
                                                 const float* __restrict__ gam,
                                                 const float* __restrict__ bet,
                                                 float* __restrict__ node0,
                                                 float* __restrict__ node1,
                                                 float* __restrict__ pool,
                                                 float* __restrict__ gout0,
                                                 float* __restrict__ gout1) {
    __shared__ float4 s[3][D4];
    const int bid = blockIdx.x;
    const int graph = (bid >= N_GRAPH) ? 1 : 0;
    const int g = bid - graph * N_GRAPH;
    const int* batch = graph ? bat1 : bat0;
    const float* h2g = h2 + (size_t)graph * NPAD * LDA;
    float* nodeout = graph ? node1 : node0;
    float* gout = graph ? gout1 : gout0;

    int lo = 0, hi = N_NODES;
    while (lo < hi) {
        int m = (lo + hi) >> 1;
        if (batch[m] < g) lo = m + 1; else hi = m;
    }
    const int p0 = lo;
    hi = N_NODES;
    while (lo < hi) {
        int m = (lo + hi) >> 1;
        if (batch[m] < g + 1) lo = m + 1; else hi = m;
    }
    const int p1 = lo;

    const int t = threadIdx.x;
    if (t < 3 * D4) {
        const int c = t % D4;
        const int rc = t / D4;
        const int d0 = c * 4;
        float4 m4 = *(const float4*)(mean + graph * DIM + d0);
        float4 r4 = *(const float4*)(rstd + graph * DIM + d0);
        float4 g4 = *(const float4*)(gam + d0);
        float4 b4 = *(const float4*)(bet + d0);
        float4 acc = {0.f, 0.f, 0.f, 0.f};
        for (int r = p0 + rc; r < p1; r += 3) {
            float4 v = *(const float4*)(h2g + (size_t)r * LDA + d0);
            v.x = (v.x - m4.x) * r4.x * g4.x + b4.x;
            v.y = (v.y - m4.y) * r4.y * g4.y + b4.y;
            v.z = (v.z - m4.z) * r4.z * g4.z + b4.z;
            v.w = (v.w - m4.w) * r4.w * g4.w + b4.w;
            *(float4*)(nodeout + (size_t)r * DIM + d0) = v;
            acc.x += v.x; acc.y += v.y; acc.z += v.z; acc.w += v.w;
        }
        s[rc][c] = acc;
    }
    __syncthreads();
    if (t < D4) {
        float4 a = s[0][t], b = s[1][t], c = s[2][t];
        const float inv = 1.0f / fmaxf((float)(p1 - p0), 1.0f);
        float4 r;
        r.x = (a.x + b.x + c.x) * inv;
        r.y = (a.y + b.y + c.y) * inv;
        r.z = (a.z + b.z + c.z) * inv;
        r.w = (a.w + b.w + c.w) * inv;
        *(float4*)(pool + (size_t)bid * DIM + t * 4) = r;
        *(float4*)(gout + (size_t)g * DIM + t * 4) = r;
    }
}

__global__ void k_pred(const float* __restrict__ pool,
                       const float* __restrict__ predW,
                       const float* __restrict__ predb,
                       float* __restrict__ out0,
                       float* __restrict__ out1) {
    int tid = blockIdx.x * blockDim.x + threadIdx.x;
    if (tid >= 2 * N_GRAPH * NTASK) return;
    int gg = tid / NTASK;
    int tt = tid % NTASK;
    int graph = (gg >= N_GRAPH) ? 1 : 0;
    int g = gg - graph * N_GRAPH;
    float s = predb[tt];
    const float* pr = pool + (size_t)gg * DIM;
    for (int k = 0; k < DIM; ++k) s += pr[k] * predW[k * NTASK + tt];
    float* outp = graph ? out1 : out0;
    outp[(size_t)g * NTASK + tt] = s;
}

static inline int cdiv(long long a, long long b) { return (int)((a + b - 1) / b); }

extern "C" void kernel_launch(void* const* d_in, const int* in_sizes, int n_in,
                              void* d_out, int out_size, void* d_ws, size_t ws_size,
                              hipStream_t stream) {
    const int* x    = (const int*)d_in[0];
    const int* ei   = (const int*)d_in[1];
    const int* ea   = (const int*)d_in[2];
    const int* bat  = (const int*)d_in[3];
    const int* x1   = (const int*)d_in[4];
    const int* ei1  = (const int*)d_in[5];
    const int* ea1  = (const int*)d_in[6];
    const int* bat1 = (const int*)d_in[7];
    const float* xemb1 = (const float*)d_in[8];
    const float* xemb2 = (const float*)d_in[9];
    const float* eemb1 = (const float*)d_in[10];
    const float* eemb2 = (const float*)d_in[11];
    const float* W1    = (const float*)d_in[12];
    const float* b1    = (const float*)d_in[13];
    const float* W2    = (const float*)d_in[14];
    const float* b2    = (const float*)d_in[15];
    const float* gamma = (const float*)d_in[16];
    const float* beta  = (const float*)d_in[17];
    const float* predW = (const float*)d_in[18];
    const float* predb = (const float*)d_in[19];
    float* out = (float*)d_out;  // reference outputs are float32

    // workspace (~260 MB; harness re-poison fill shows d_ws ≈ 476 MiB)
    char* ws = (char*)d_ws;
    size_t off = 0;
    auto take = [&](size_t bytes) -> char* {
        char* p = ws + off;
        off += (bytes + 255) & ~(size_t)255;
        return p;
    };
    const size_t PLANE = (size_t)MT2 * KST1 * 4096;        // batched hi-plane, ushorts
    const size_t BUFSZ = PLANE * 2 * 2;                    // hi+lo planes, bytes (~122 MB)
    char* bufA = take(BUFSZ);
    char* bufB = take(BUFSZ);
    float* pool   = (float*)take((size_t)2 * N_GRAPH * DIM * 4);
    double* bnsum = (double*)take(2 * DIM * 8 * 2);
    double* bnsq  = bnsum + 2 * DIM;
    float* bnmean = (float*)take(2 * DIM * 4 * 2);
    float* bnrstd = bnmean + 2 * DIM;
    // packed weight planes
    const size_t W1P = (size_t)NLAYER * NT1 * KB1 * 1024;  // 1,024,000
    const size_t W2P = (size_t)NLAYER * NT2 * KB2 * 1024;  // 1,167,360
    ushort_t* w1hi = (ushort_t*)take(W1P * 2);
    ushort_t* w1lo = (ushort_t*)take(W1P * 2);
    ushort_t* w2hi = (ushort_t*)take(W2P * 2);
    ushort_t* w2lo = (ushort_t*)take(W2P * 2);
    // CSR buffers
    int* deg     = (int*)take(N_NODES * 4);
    int* excl    = (int*)take(N_NODES * 4);
    int* blksum  = (int*)take(256 * 4);
    int* blkoff  = (int*)take(256 * 4);
    int* fillptr = (int*)take(N_NODES * 4);
    int* rowptr0 = (int*)take((N_NODES + 1) * 4);
    int* csrc0   = (int*)take(N_EDGES * 4);
    int* cea0    = (int*)take(N_EDGES * 4);
    int* rowptr1 = (int*)take((N_NODES + 1) * 4);
    int* csrc1   = (int*)take(N_EDGES * 4);
    int* cea1    = (int*)take(N_EDGES * 4);
    (void)ws_size; (void)in_sizes; (void)n_in; (void)out_size;

    const int TB = 256;
    const int gE   = cdiv(N_EDGES, TB);
    const int gScan = cdiv(N_NODES, TB);
    const int gScan3 = cdiv(N_NODES + 1, TB);
    const int gGath = cdiv((long long)2 * N_NODES * D4P, TB);
    const int NWG1 = NT1 * MT2;              // 3910
    const int NWG2 = NT2 * MT2;              // 2346

    // pack weights once per call
    k_pack_w<<<cdiv((long long)W1P, TB), TB, 0, stream>>>(W1, w1hi, w1lo, DIM, DIM2, KB1, NT1, (int)W1P);
    k_pack_w<<<cdiv((long long)W2P, TB), TB, 0, stream>>>(W2, w2hi, w2lo, DIM2, DIM, KB2, NT2, (int)W2P);

    // build CSR once per graph
    auto build_csr = [&](const int* eip, const int* eap, int* rowptr, int* csrc, int* cea) {
        hipMemsetAsync(deg, 0, N_NODES * 4, stream);
        k_deg<<<gE, TB, 0, stream>>>(eip, deg);
        k_scan1<<<gScan, TB, 0, stream>>>(deg, excl, blksum);
        k_scan2<<<1, 256, 0, stream>>>(blksum, blkoff, gScan);
        k_scan3<<<gScan3, TB, 0, stream>>>(excl, blkoff, rowptr, fillptr);
        k_fill<<<gE, TB, 0, stream>>>(eip, eap, fillptr, csrc, cea);
    };
    build_csr(ei, ea, rowptr0, csrc0, cea0);
    build_csr(ei1, ea1, rowptr1, csrc1, cea1);

    // zero BN accumulators once; k_bn_finalize re-zeroes after each layer
    hipMemsetAsync(bnsum, 0, 2 * DIM * 8 * 2, stream);

    const size_t GT = (size_t)N_GRAPH * NTASK;       // 20000
    const size_t GD = (size_t)N_GRAPH * DIM;         // 600000
    const size_t ND = (size_t)N_NODES * DIM;         // 15000000
    float* out_pred0  = out;
    float* out_graph0 = out + GT;
    float* out_node0  = out + GT + GD;
    float* out_pred1  = out + GT + GD + ND;
    float* out_graph1 = out + 2 * GT + GD + ND;
    float* out_node1  = out + 2 * GT + 2 * GD + ND;

    // single BATCHED layer loop over both graphs
    for (int l = 0; l < NLAYER; ++l) {
        char* pb = (l & 1) ? bufA : bufB;   // planes, then h2
        char* yb = (l & 1) ? bufB : bufA;   // gather input (h2 of l-1), then y
        ushort_t* aghi = (ushort_t*)pb;
        ushort_t* aglo = aghi + PLANE;
        const float* gin = (const float*)yb;
        ushort_t* yv = (ushort_t*)yb;
        float* h2v = (float*)pb;
        const float* ee1l = eemb1 + (size_t)l * 6 * DIM;
        const float* ee2l = eemb2 + (size_t)l * 3 * DIM;
        if (l == 0)
            k_gather_agg<true><<<gGath, TB, 0, stream>>>(
                rowptr0, csrc0, cea0, rowptr1, csrc1, cea1, x, x1, xemb1, xemb2,
                nullptr, ee1l, ee2l, ee1l + 4 * DIM, ee2l,
                nullptr, nullptr, nullptr, nullptr, aghi, aglo, gGath);
        else
            k_gather_agg<false><<<gGath, TB, 0, stream>>>(
                rowptr0, csrc0, cea0, rowptr1, csrc1, cea1, x, x1, xemb1, xemb2,
                gin, ee1l, ee2l, ee1l + 4 * DIM, ee2l,
                bnmean, bnrstd, gamma + (size_t)(l - 1) * DIM, beta + (size_t)(l - 1) * DIM,
                aghi, aglo, gGath);
        // GEMM1: y = relu(agg @ W1[l] + b1[l]); y written BLOCKED (ksout=KST2)
        k_gemm_mfma<true, true, false, ushort_t>
            <<<NWG1, TB, 0, stream>>>(
                aghi, aglo,
                w1hi + (size_t)l * NT1 * KB1 * 1024, w1lo + (size_t)l * NT1 * KB1 * 1024,
                b1 + (size_t)l * DIM2, yv, nullptr, nullptr,
                N_NODES, DIM2, KST1, KB1, NT1, NWG1, 0, 608, KST2, MT_TILES);
        // GEMM2: h2 = y @ W2[l] + b2[l] + fused per-graph BN stats
        k_gemm_mfma<false, false, true, float>
            <<<NWG2, TB, 0, stream>>>(
                yv, yv,
                w2hi + (size_t)l * NT2 * KB2 * 1024, w2lo + (size_t)l * NT2 * KB2 * 1024,
                b2 + (size_t)l * DIM, h2v, bnsum, bnsq,
                N_NODES, DIM, KST2, KB2, NT2, NWG2, LDA, 304, 0, MT_TILES);
        k_bn_finalize<<<3, 256, 0, stream>>>(bnsum, bnsq, bnmean, bnrstd);
    }
    // final h2 lives in bufB (l=4 even -> pb=bufB)
    k_bn_pool<<<2 * N_GRAPH, TB, 0, stream>>>(
        (const float*)bufB, bat, bat1, bnmean, bnrstd,
        gamma + (size_t)(NLAYER - 1) * DIM, beta + (size_t)(NLAYER - 1) * DIM,
        out_node0, out_node1, pool, out_graph0, out_graph1);
    k_pred<<<cdiv((long long)2 * N_GRAPH * NTASK, TB), TB, 0, stream>>>(
        pool, predW, predb, out_pred0, out_pred1);
}

// Round 12
// 1821.898 us; speedup vs baseline: 1.1443x; 1.1443x over previous
//
#include <hip/hip_runtime.h>
#include <hip/hip_bf16.h>

typedef unsigned short ushort_t;
typedef short v8s __attribute__((ext_vector_type(8)));
typedef unsigned short v8u __attribute__((ext_vector_type(8)));
typedef unsigned short v4u __attribute__((ext_vector_type(4)));
typedef float v4f __attribute__((ext_vector_type(4)));

#define N_NODES 50000
#define N_EDGES 100000
#define N_GRAPH 2000
#define DIM     300
#define DIM2    600
#define NLAYER  5
#define NTASK   10
#define D4      75   // DIM/4
#define D4P     80   // padded chunk count for split-A planes (K-pad to 320)

// BATCHED over both GNNs: row space [0,NPAD) = graph0, [NPAD,2*NPAD) = graph1.
// fp32 node buffers (h2): row-major, LDA=304 (1216 B rows), 2*NPAD rows.
// bf16 MFMA operands (gather planes, y, weights): global memory in the GEMM's
// LDS tile layout [mt][ks][kb4][m128][j8].
// GEMM structure (R10, best measured): A fragments direct global->register
// (contiguous 16 B/lane, L2-hot); B LDS-double-buffered via global_load_lds.
// R11's fully barrier-free variant (B also direct) REGRESSED ~20%: 16 per-lane
// VMEM loads' vmcnt waits sit in front of each MFMA cluster and can't be
// pipelined past the accumulator chain — exposed L2 latency per K-step.
#define LDA  304
#define NPAD 50048   // MT_TILES*128
#define KST1 10      // GEMM1 K-steps (K=320)
#define KST2 19      // GEMM2 K-steps (K=608) = y's blocked factor

#define KB1 40
#define NT1 5
#define KB2 76
#define NT2 3
#define MT_TILES 391    // ceil(50000/128) per graph
#define MT2      782    // both graphs

#define AS1 __attribute__((address_space(1)))
#define AS3 __attribute__((address_space(3)))
static __device__ __forceinline__ void gload_lds16(const void* g, void* l) {
    __builtin_amdgcn_global_load_lds((AS1 void*)(g), (AS3 void*)(l), 16, 0, 0);
}

static __device__ __forceinline__ ushort_t f2bf(float f) {
    unsigned int u;
    __builtin_memcpy(&u, &f, 4);
    unsigned int lsb = (u >> 16) & 1u;
    u += 0x7fffu + lsb;
    return (ushort_t)(u >> 16);
}
// split fp32 into truncated-hi bf16 + residual bf16 (hi + lo ~= f to ~2^-17)
static __device__ __forceinline__ void split2(float f, ushort_t& h, ushort_t& l) {
    unsigned int u;
    __builtin_memcpy(&u, &f, 4);
    h = (ushort_t)(u >> 16);
    unsigned int um = u & 0xFFFF0000u;
    float hf;
    __builtin_memcpy(&hf, &um, 4);
    float lf = f - hf;
    unsigned int ul;
    __builtin_memcpy(&ul, &lf, 4);
    l = (ushort_t)(ul >> 16);
}

// bijective XCD-grouping swizzle (m204)
static __device__ __forceinline__ int swz_wgid(int orig, int nwg) {
    int xcd = orig & 7;
    int seq = orig >> 3;
    int q = nwg >> 3, r = nwg & 7;
    int base = (xcd < r) ? xcd * (q + 1) : r * (q + 1) + (xcd - r) * q;
    return base + seq;
}

// ---------------- CSR build (once per launch) ----------------
__global__ void k_deg(const int* __restrict__ ei, int* __restrict__ deg) {
    int e = blockIdx.x * blockDim.x + threadIdx.x;
    if (e >= N_EDGES) return;
    atomicAdd(&deg[ei[N_EDGES + e]], 1);
}

__global__ void k_scan1(const int* __restrict__ deg, int* __restrict__ excl,
                        int* __restrict__ blksum) {
    __shared__ int s[256];
    int i = blockIdx.x * 256 + threadIdx.x;
    int v = (i < N_NODES) ? deg[i] : 0;
    s[threadIdx.x] = v;
    __syncthreads();
#pragma unroll
    for (int o = 1; o < 256; o <<= 1) {
        int t = (threadIdx.x >= o) ? s[threadIdx.x - o] : 0;
        __syncthreads();
        s[threadIdx.x] += t;
        __syncthreads();
    }
    if (i < N_NODES) excl[i] = s[threadIdx.x] - v;
    if (threadIdx.x == 255) blksum[blockIdx.x] = s[255];
}

__global__ void k_scan2(int* __restrict__ blksum, int* __restrict__ blkoff, int nblk) {
    __shared__ int s[256];
    int v = (threadIdx.x < nblk) ? blksum[threadIdx.x] : 0;
    s[threadIdx.x] = v;
    __syncthreads();
#pragma unroll
    for (int o = 1; o < 256; o <<= 1) {
        int t = (threadIdx.x >= o) ? s[threadIdx.x - o] : 0;
        __syncthreads();
        s[threadIdx.x] += t;
        __syncthreads();
    }
    if (threadIdx.x < nblk) blkoff[threadIdx.x] = s[threadIdx.x] - v;
}

__global__ void k_scan3(const int* __restrict__ excl, const int* __restrict__ blkoff,
                        int* __restrict__ rowptr, int* __restrict__ fillptr) {
    int i = blockIdx.x * blockDim.x + threadIdx.x;
    if (i > N_NODES) return;
    int v = (i < N_NODES) ? (excl[i] + blkoff[i >> 8]) : N_EDGES;
    rowptr[i] = v;
    if (i < N_NODES) fillptr[i] = v;
}

__global__ void k_fill(const int* __restrict__ ei, const int* __restrict__ ea,
                       int* __restrict__ fillptr,
                       int* __restrict__ csrc, int* __restrict__ cea) {
    int e = blockIdx.x * blockDim.x + threadIdx.x;
    if (e >= N_EDGES) return;
    int dst = ei[N_EDGES + e];
    int pos = atomicAdd(&fillptr[dst], 1);
    csrc[pos] = ei[e];
    cea[pos] = (ea[2 * e + 0] << 16) | ea[2 * e + 1];
}

// BATCHED gather over both graphs. Grid is XCD-swizzled (verified win, R11):
// consecutive node blocks stay on one XCD so the 64 B lines of the blocked
// plane output are assembled in a single L2.
// EMB (layer 0): h computed inline from xemb tables (L2-resident).
// !EMB: BN(+ReLU) of previous layer applied on the fly.
template <bool EMB>
__global__ void k_gather_agg(const int* __restrict__ rowptr0,
                             const int* __restrict__ csrc0,
                             const int* __restrict__ cea0,
                             const int* __restrict__ rowptr1,
                             const int* __restrict__ csrc1,
                             const int* __restrict__ cea1,
                             const int* __restrict__ x0,
                             const int* __restrict__ x1,
                             const float* __restrict__ xe1,
                             const float* __restrict__ xe2,
                             const float* __restrict__ hin,
                             const float* __restrict__ ee1,
                             const float* __restrict__ ee2,
                             const float* __restrict__ ee1sl,
                             const float* __restrict__ ee2sl,
                             const float* __restrict__ bnmean,
                             const float* __restrict__ bnrstd,
                             const float* __restrict__ bngam,
                             const float* __restrict__ bnbet,
                             ushort_t* __restrict__ aghi,
                             ushort_t* __restrict__ aglo,
                             int nwg) {
    int wgid = swz_wgid(blockIdx.x, nwg);
    int tid = wgid * blockDim.x + threadIdx.x;
    if (tid >= 2 * N_NODES * D4P) return;
    int gi = tid / D4P;
    int c = tid % D4P;
    int graph = (gi >= N_NODES) ? 1 : 0;
    int ln = gi - graph * N_NODES;          // local node id
    int row = graph * NPAD + ln;            // batched buffer row
    int d0 = c * 4;
    const int mt = row >> 7, m = row & 127;
    const int ks = d0 >> 5, kb = (d0 >> 3) & 3, jq = d0 & 7;
    const size_t off = (((size_t)mt * KST1 + ks) * 4 + kb) * 1024 + m * 8 + jq;
    if (c >= D4) {  // K-pad cols 300..319 -> exact zeros
        v4u z = (v4u){0, 0, 0, 0};
        *(v4u*)(aghi + off) = z;
        *(v4u*)(aglo + off) = z;
        return;
    }
    const int* rowptr = graph ? rowptr1 : rowptr0;
    const int* csrc   = graph ? csrc1   : csrc0;
    const int* cea    = graph ? cea1    : cea0;
    const int* xp     = graph ? x1      : x0;

    float4 m4, r4, g4, b4;
    if (!EMB) {
        const int bo = graph * DIM + d0;
        m4 = *(const float4*)(bnmean + bo);
        r4 = *(const float4*)(bnrstd + bo);
        g4 = *(const float4*)(bngam + d0);
        b4 = *(const float4*)(bnbet + d0);
    }
    auto hval = [&](int node) -> float4 {
        if (EMB) {
            int i0 = xp[node * 2 + 0];
            int i1 = xp[node * 2 + 1];
            float4 a = *(const float4*)(xe1 + (size_t)i0 * DIM + d0);
            float4 b = *(const float4*)(xe2 + (size_t)i1 * DIM + d0);
            float4 o;
            o.x = a.x + b.x; o.y = a.y + b.y; o.z = a.z + b.z; o.w = a.w + b.w;
            return o;
        } else {
            float4 v = *(const float4*)(hin + (size_t)(graph * NPAD + node) * LDA + d0);
            v.x = fmaxf((v.x - m4.x) * r4.x * g4.x + b4.x, 0.f);
            v.y = fmaxf((v.y - m4.y) * r4.y * g4.y + b4.y, 0.f);
            v.z = fmaxf((v.z - m4.z) * r4.z * g4.z + b4.z, 0.f);
            v.w = fmaxf((v.w - m4.w) * r4.w * g4.w + b4.w, 0.f);
            return v;
        }
    };
    float4 a = hval(ln);
    float4 e1 = *(const float4*)(ee1sl + d0);
    float4 e2 = *(const float4*)(ee2sl + d0);
    a.x += e1.x + e2.x; a.y += e1.y + e2.y; a.z += e1.z + e2.z; a.w += e1.w + e2.w;
    int p0 = rowptr[ln], p1 = rowptr[ln + 1];
    for (int p = p0; p < p1; ++p) {
        int src = csrc[p];
        int pk = cea[p];
        int a0 = pk >> 16, a1 = pk & 0xFFFF;
        float4 hv = hval(src);
        float4 f1 = *(const float4*)(ee1 + (size_t)a0 * DIM + d0);
        float4 f2 = *(const float4*)(ee2 + (size_t)a1 * DIM + d0);
        a.x += hv.x + f1.x + f2.x;
        a.y += hv.y + f1.y + f2.y;
        a.z += hv.z + f1.z + f2.z;
        a.w += hv.w + f1.w + f2.w;
    }
    float av[4] = {a.x, a.y, a.z, a.w};
    v4u hh, ll;
#pragma unroll
    for (int i = 0; i < 4; ++i) {
        ushort_t uh, ul;
        split2(av[i], uh, ul);
        hh[i] = uh;
        ll[i] = ul;
    }
    *(v4u*)(aghi + off) = hh;
    *(v4u*)(aglo + off) = ll;
}

// Pack weights W [L][K][N] fp32 -> hi/lo bf16 planes, layout [l][nt][kb][n(128)][j(8)]
__global__ void k_pack_w(const float* __restrict__ W,
                         ushort_t* __restrict__ hi,
                         ushort_t* __restrict__ lo,
                         int K, int N, int KBv, int NTv, int total) {
    int idx = blockIdx.x * blockDim.x + threadIdx.x;
    if (idx >= total) return;
    int j = idx & 7;
    int n = (idx >> 3) & 127;
    int tmp = idx >> 10;
    int kb = tmp % KBv; tmp /= KBv;
    int nt = tmp % NTv;
    int l = tmp / NTv;
    int k = kb * 8 + j;
    int ng = nt * 128 + n;
    float v = 0.f;
    if (k < K && ng < N) v = W[((size_t)l * K + k) * N + ng];
    ushort_t h, lw;
    split2(v, h, lw);
    hi[idx] = h;
    lo[idx] = lw;
}

// MFMA split-precision GEMM, BATCHED (mt in [0, 2*mtHalf)). R10 structure:
//   A: blocked global; fragments loaded DIRECTLY to registers.
//   B: LDS double-buffered via global_load_lds.
// ORDERING INVARIANT (vmcnt is FIFO): A-frag loads issued BEFORE the B
// prefetch, pinned with sched_barrier(0) — the auto-waitcnt before MFMA waits
// A only, leaving B in flight under the MFMA cluster.
// BNSTAT: per-graph per-column sum/sumsq fused into the epilogue.
template <bool RELU, bool SPLITA, bool BNSTAT, typename OT>
__global__ __launch_bounds__(256) void k_gemm_mfma(
        const ushort_t* __restrict__ Ahi,
        const ushort_t* __restrict__ Alo,
        const ushort_t* __restrict__ Bhi,
        const ushort_t* __restrict__ Blo,
        const float* __restrict__ bias,
        OT* __restrict__ C,
        double* __restrict__ bnsum,
        double* __restrict__ bnsq,
        int M, int N, int Ksteps, int KBv, int NTv, int nwg,
        int ldc, int ncap, int ksout, int mtHalf) {
    alignas(16) __shared__ ushort_t sBhi[8192];   // 2 x [kb4][n128][j8]
    alignas(16) __shared__ ushort_t sBlo[8192];

    const int wgid = swz_wgid(blockIdx.x, nwg);
    const int nt = wgid % NTv;
    const int mt = wgid / NTv;
    const int t = threadIdx.x;

    const int w = t >> 6;
    const int lane = t & 63;
    const int wm = w >> 1;
    const int wn = w & 1;
    const int quad = lane >> 4;
    const int lr = lane & 15;

    v4f acc[4][4];
#pragma unroll
    for (int i = 0; i < 4; ++i)
#pragma unroll
        for (int j = 0; j < 4; ++j) acc[i][j] = (v4f){0.f, 0.f, 0.f, 0.f};

    const int aoff = quad * 1024 + (wm * 64 + lr) * 8;

    auto stageB = [&](int buf, int ks) {
        const int bo = buf * 4096;
        const size_t bbase = ((size_t)nt * KBv + ks * 4) * 1024;
#pragma unroll
        for (int p = 0; p < 2; ++p) {
            int o = p * 2048 + t * 8;
            gload_lds16(Bhi + bbase + o, &sBhi[bo + o]);
            gload_lds16(Blo + bbase + o, &sBlo[bo + o]);
        }
    };

    stageB(0, 0);
    __syncthreads();   // buf0 ready
    int cur = 0;
    for (int ks = 0; ks < Ksteps; ++ks) {
        // A fragments straight from global — issued FIRST (FIFO vmcnt)
        const ushort_t* ah = Ahi + ((size_t)mt * Ksteps + ks) * 4096 + aoff;
        const ushort_t* al = SPLITA ? (Alo + ((size_t)mt * Ksteps + ks) * 4096 + aoff) : nullptr;
        v8s a_hi[4], a_lo[4];
#pragma unroll
        for (int s = 0; s < 4; ++s) {
            a_hi[s] = *(const v8s*)(ah + s * 128);
            if (SPLITA) a_lo[s] = *(const v8s*)(al + s * 128);
        }
        __builtin_amdgcn_sched_barrier(0);   // pin: A-loads stay BEFORE B prefetch
        if (ks + 1 < Ksteps) stageB(cur ^ 1, ks + 1);   // async, lands under MFMA
        const int bo = cur * 4096;
#pragma unroll
        for (int sj = 0; sj < 4; ++sj) {
            v8s bh = *(const v8s*)&sBhi[bo + quad * 1024 + (wn * 64 + sj * 16 + lr) * 8];
            v8s bl = *(const v8s*)&sBlo[bo + quad * 1024 + (wn * 64 + sj * 16 + lr) * 8];
#pragma unroll
            for (int si = 0; si < 4; ++si) {
                acc[si][sj] = __builtin_amdgcn_mfma_f32_16x16x32_bf16(
                    a_hi[si], bh, acc[si][sj], 0, 0, 0);
                acc[si][sj] = __builtin_amdgcn_mfma_f32_16x16x32_bf16(
                    a_hi[si], bl, acc[si][sj], 0, 0, 0);
                if (SPLITA)
                    acc[si][sj] = __builtin_amdgcn_mfma_f32_16x16x32_bf16(
                        a_lo[si], bh, acc[si][sj], 0, 0, 0);
            }
        }
        __syncthreads();   // B prefetch drained (covered by MFMA cluster)
        cur ^= 1;
    }

    const int graph = (mt >= mtHalf) ? 1 : 0;
    float bsum[4], bsq[4];
    if (BNSTAT) {
#pragma unroll
        for (int sj = 0; sj < 4; ++sj) { bsum[sj] = 0.f; bsq[sj] = 0.f; }
    }
#pragma unroll
    for (int sj = 0; sj < 4; ++sj) {
        int col = nt * 128 + wn * 64 + sj * 16 + lr;
        if (col >= ncap) continue;
        float bv = (col < N) ? bias[col] : 0.f;   // pad cols -> exact 0
        size_t yb = 0;
        if (sizeof(OT) == 2)
            yb = (((size_t)mt * ksout + (col >> 5)) * 4 + ((col >> 3) & 3)) * 1024 + (col & 7);
#pragma unroll
        for (int si = 0; si < 4; ++si) {
#pragma unroll
            for (int r = 0; r < 4; ++r) {
                int m = wm * 64 + si * 16 + quad * 4 + r;
                size_t row = (size_t)mt * 128 + m;
                float v = acc[si][sj][r] + bv;
                if (RELU) v = fmaxf(v, 0.f);
                if (BNSTAT) {
                    int lrow = (mt - graph * mtHalf) * 128 + m;   // per-graph row
                    if (lrow < M) { bsum[sj] += v; bsq[sj] += v * v; }
                }
                if (sizeof(OT) == 2)
                    ((ushort_t*)C)[yb + m * 8] = f2bf(v);
                else
                    ((float*)C)[row * ldc + col] = v;
            }
        }
    }
    if (BNSTAT) {
        float* sred = (float*)sBhi;   // K-loop done; LDS reusable
#pragma unroll
        for (int sj = 0; sj < 4; ++sj) {
            bsum[sj] += __shfl_xor(bsum[sj], 16);
            bsum[sj] += __shfl_xor(bsum[sj], 32);
            bsq[sj]  += __shfl_xor(bsq[sj], 16);
            bsq[sj]  += __shfl_xor(bsq[sj], 32);
        }
        if (quad == 0) {
#pragma unroll
            for (int sj = 0; sj < 4; ++sj) {
                int idx = wm * 128 + wn * 64 + sj * 16 + lr;
                sred[idx] = bsum[sj];
                sred[256 + idx] = bsq[sj];
            }
        }
        __syncthreads();
        if (t < 128) {
            float s = sred[t] + sred[128 + t];
            float q = sred[256 + t] + sred[256 + 128 + t];
            int col = nt * 128 + t;
            if (col < N) {
                atomicAdd(&bnsum[graph * N + col], (double)s);
                atomicAdd(&bnsq[graph * N + col], (double)q);
            }
        }
    }
}

// finalize BN stats for BOTH graphs (2*DIM cols) AND zero accumulators
__global__ void k_bn_finalize(double* __restrict__ sum,
                              double* __restrict__ sumsq,
                              float* __restrict__ mean,
                              float* __restrict__ rstd) {
    int d = blockIdx.x * blockDim.x + threadIdx.x;
    if (d >= 2 * DIM) return;
    double mu = sum[d] / (double)N_NODES;
    double var = sumsq[d] / (double)N_NODES - mu * mu;
    if (var < 0.0) var = 0.0;
    mean[d] = (float)mu;
    rstd[d] = (float)(1.0 / sqrt(var + 1e-5));
    sum[d] = 0.0;
    sumsq[d] = 0.0;
}

// Final layer, BATCHED: fused BN (no relu) + out_node write + segmented mean pool.
__global__ __launch_bounds__(256) void k_bn_pool(const float* __restrict__ h2,
                                                 const int* __restrict__ bat0,
                                                 const int* __restrict__ bat1,
                                                 const float* __restrict__ mean,
                                                 const float* __restrict__ rstd,
                                                 const float* __restrict__ gam,
                                                 const float* __restrict__ bet,
                                                 float* __restrict__ node0,
                                                 float* __restrict__ node1,
                                                 float* __restrict__ pool,
                                                 float* __restrict__ gout0,
                                                 float* __restrict__ gout1) {
    __shared__ float4 s[3][D4];
    const int bid = blockIdx.x;
    const int graph = (bid >= N_GRAPH) ? 1 : 0;
    const int g = bid - graph * N_GRAPH;
    const int* batch = graph ? bat1 : bat0;
    const float* h2g = h2 + (size_t)graph * NPAD * LDA;
    float* nodeout = graph ? node1 : node0;
    float* gout = graph ? gout1 : gout0;

    int lo = 0, hi = N_NODES;
    while (lo < hi) {
        int m = (lo + hi) >> 1;
        if (batch[m] < g) lo = m + 1; else hi = m;
    }
    const int p0 = lo;
    hi = N_NODES;
    while (lo < hi) {
        int m = (lo + hi) >> 1;
        if (batch[m] < g + 1) lo = m + 1; else hi = m;
    }
    const int p1 = lo;

    const int t = threadIdx.x;
    if (t < 3 * D4) {
        const int c = t % D4;
        const int rc = t / D4;
        const int d0 = c * 4;
        float4 m4 = *(const float4*)(mean + graph * DIM + d0);
        float4 r4 = *(const float4*)(rstd + graph * DIM + d0);
        float4 g4 = *(const float4*)(gam + d0);
        float4 b4 = *(const float4*)(bet + d0);
        float4 acc = {0.f, 0.f, 0.f, 0.f};
        for (int r = p0 + rc; r < p1; r += 3) {
            float4 v = *(const float4*)(h2g + (size_t)r * LDA + d0);
            v.x = (v.x - m4.x) * r4.x * g4.x + b4.x;
            v.y = (v.y - m4.y) * r4.y * g4.y + b4.y;
            v.z = (v.z - m4.z) * r4.z * g4.z + b4.z;
            v.w = (v.w - m4.w) * r4.w * g4.w + b4.w;
            *(float4*)(nodeout + (size_t)r * DIM + d0) = v;
            acc.x += v.x; acc.y += v.y; acc.z += v.z; acc.w += v.w;
        }
        s[rc][c] = acc;
    }
    __syncthreads();
    if (t < D4) {
        float4 a = s[0][t], b = s[1][t], c = s[2][t];
        const float inv = 1.0f / fmaxf((float)(p1 - p0), 1.0f);
        float4 r;
        r.x = (a.x + b.x + c.x) * inv;
        r.y = (a.y + b.y + c.y) * inv;
        r.z = (a.z + b.z + c.z) * inv;
        r.w = (a.w + b.w + c.w) * inv;
        *(float4*)(pool + (size_t)bid * DIM + t * 4) = r;
        *(float4*)(gout + (size_t)g * DIM + t * 4) = r;
    }
}

__global__ void k_pred(const float* __restrict__ pool,
                       const float* __restrict__ predW,
                       const float* __restrict__ predb,
                       float* __restrict__ out0,
                       float* __restrict__ out1) {
    int tid = blockIdx.x * blockDim.x + threadIdx.x;
    if (tid >= 2 * N_GRAPH * NTASK) return;
    int gg = tid / NTASK;
    int tt = tid % NTASK;
    int graph = (gg >= N_GRAPH) ? 1 : 0;
    int g = gg - graph * N_GRAPH;
    float s = predb[tt];
    const float* pr = pool + (size_t)gg * DIM;
    for (int k = 0; k < DIM; ++k) s += pr[k] * predW[k * NTASK + tt];
    float* outp = graph ? out1 : out0;
    outp[(size_t)g * NTASK + tt] = s;
}

static inline int cdiv(long long a, long long b) { return (int)((a + b - 1) / b); }

extern "C" void kernel_launch(void* const* d_in, const int* in_sizes, int n_in,
                              void* d_out, int out_size, void* d_ws, size_t ws_size,
                              hipStream_t stream) {
    const int* x    = (const int*)d_in[0];
    const int* ei   = (const int*)d_in[1];
    const int* ea   = (const int*)d_in[2];
    const int* bat  = (const int*)d_in[3];
    const int* x1   = (const int*)d_in[4];
    const int* ei1  = (const int*)d_in[5];
    const int* ea1  = (const int*)d_in[6];
    const int* bat1 = (const int*)d_in[7];
    const float* xemb1 = (const float*)d_in[8];
    const float* xemb2 = (const float*)d_in[9];
    const float* eemb1 = (const float*)d_in[10];
    const float* eemb2 = (const float*)d_in[11];
    const float* W1    = (const float*)d_in[12];
    const float* b1    = (const float*)d_in[13];
    const float* W2    = (const float*)d_in[14];
    const float* b2    = (const float*)d_in[15];
    const float* gamma = (const float*)d_in[16];
    const float* beta  = (const float*)d_in[17];
    const float* predW = (const float*)d_in[18];
    const float* predb = (const float*)d_in[19];
    float* out = (float*)d_out;  // reference outputs are float32

    // workspace (~260 MB; harness re-poison fill shows d_ws ≈ 476 MiB)
    char* ws = (char*)d_ws;
    size_t off = 0;
    auto take = [&](size_t bytes) -> char* {
        char* p = ws + off;
        off += (bytes + 255) & ~(size_t)255;
        return p;
    };
    const size_t PLANE = (size_t)MT2 * KST1 * 4096;        // batched hi-plane, ushorts
    const size_t BUFSZ = PLANE * 2 * 2;                    // hi+lo planes, bytes (~122 MB)
    char* bufA = take(BUFSZ);
    char* bufB = take(BUFSZ);
    float* pool   = (float*)take((size_t)2 * N_GRAPH * DIM * 4);
    double* bnsum = (double*)take(2 * DIM * 8 * 2);
    double* bnsq  = bnsum + 2 * DIM;
    float* bnmean = (float*)take(2 * DIM * 4 * 2);
    float* bnrstd = bnmean + 2 * DIM;
    // packed weight planes
    const size_t W1P = (size_t)NLAYER * NT1 * KB1 * 1024;  // 1,024,000
    const size_t W2P = (size_t)NLAYER * NT2 * KB2 * 1024;  // 1,167,360
    ushort_t* w1hi = (ushort_t*)take(W1P * 2);
    ushort_t* w1lo = (ushort_t*)take(W1P * 2);
    ushort_t* w2hi = (ushort_t*)take(W2P * 2);
    ushort_t* w2lo = (ushort_t*)take(W2P * 2);
    // CSR buffers
    int* deg     = (int*)take(N_NODES * 4);
    int* excl    = (int*)take(N_NODES * 4);
    int* blksum  = (int*)take(256 * 4);
    int* blkoff  = (int*)take(256 * 4);
    int* fillptr = (int*)take(N_NODES * 4);
    int* rowptr0 = (int*)take((N_NODES + 1) * 4);
    int* csrc0   = (int*)take(N_EDGES * 4);
    int* cea0    = (int*)take(N_EDGES * 4);
    int* rowptr1 = (int*)take((N_NODES + 1) * 4);
    int* csrc1   = (int*)take(N_EDGES * 4);
    int* cea1    = (int*)take(N_EDGES * 4);
    (void)ws_size; (void)in_sizes; (void)n_in; (void)out_size;

    const int TB = 256;
    const int gE   = cdiv(N_EDGES, TB);
    const int gScan = cdiv(N_NODES, TB);
    const int gScan3 = cdiv(N_NODES + 1, TB);
    const int gGath = cdiv((long long)2 * N_NODES * D4P, TB);
    const int NWG1 = NT1 * MT2;              // 3910
    const int NWG2 = NT2 * MT2;              // 2346

    // pack weights once per call
    k_pack_w<<<cdiv((long long)W1P, TB), TB, 0, stream>>>(W1, w1hi, w1lo, DIM, DIM2, KB1, NT1, (int)W1P);
    k_pack_w<<<cdiv((long long)W2P, TB), TB, 0, stream>>>(W2, w2hi, w2lo, DIM2, DIM, KB2, NT2, (int)W2P);

    // build CSR once per graph
    auto build_csr = [&](const int* eip, const int* eap, int* rowptr, int* csrc, int* cea) {
        hipMemsetAsync(deg, 0, N_NODES * 4, stream);
        k_deg<<<gE, TB, 0, stream>>>(eip, deg);
        k_scan1<<<gScan, TB, 0, stream>>>(deg, excl, blksum);
        k_scan2<<<1, 256, 0, stream>>>(blksum, blkoff, gScan);
        k_scan3<<<gScan3, TB, 0, stream>>>(excl, blkoff, rowptr, fillptr);
        k_fill<<<gE, TB, 0, stream>>>(eip, eap, fillptr, csrc, cea);
    };
    build_csr(ei, ea, rowptr0, csrc0, cea0);
    build_csr(ei1, ea1, rowptr1, csrc1, cea1);

    // zero BN accumulators once; k_bn_finalize re-zeroes after each layer
    hipMemsetAsync(bnsum, 0, 2 * DIM * 8 * 2, stream);

    const size_t GT = (size_t)N_GRAPH * NTASK;       // 20000
    const size_t GD = (size_t)N_GRAPH * DIM;         // 600000
    const size_t ND = (size_t)N_NODES * DIM;         // 15000000
    float* out_pred0  = out;
    float* out_graph0 = out + GT;
    float* out_node0  = out + GT + GD;
    float* out_pred1  = out + GT + GD + ND;
    float* out_graph1 = out + 2 * GT + GD + ND;
    float* out_node1  = out + 2 * GT + 2 * GD + ND;

    // single BATCHED layer loop over both graphs
    for (int l = 0; l < NLAYER; ++l) {
        char* pb = (l & 1) ? bufA : bufB;   // planes, then h2
        char* yb = (l & 1) ? bufB : bufA;   // gather input (h2 of l-1), then y
        ushort_t* aghi = (ushort_t*)pb;
        ushort_t* aglo = aghi + PLANE;
        const float* gin = (const float*)yb;
        ushort_t* yv = (ushort_t*)yb;
        float* h2v = (float*)pb;
        const float* ee1l = eemb1 + (size_t)l * 6 * DIM;
        const float* ee2l = eemb2 + (size_t)l * 3 * DIM;
        if (l == 0)
            k_gather_agg<true><<<gGath, TB, 0, stream>>>(
                rowptr0, csrc0, cea0, rowptr1, csrc1, cea1, x, x1, xemb1, xemb2,
                nullptr, ee1l, ee2l, ee1l + 4 * DIM, ee2l,
                nullptr, nullptr, nullptr, nullptr, aghi, aglo, gGath);
        else
            k_gather_agg<false><<<gGath, TB, 0, stream>>>(
                rowptr0, csrc0, cea0, rowptr1, csrc1, cea1, x, x1, xemb1, xemb2,
                gin, ee1l, ee2l, ee1l + 4 * DIM, ee2l,
                bnmean, bnrstd, gamma + (size_t)(l - 1) * DIM, beta + (size_t)(l - 1) * DIM,
                aghi, aglo, gGath);
        // GEMM1: y = relu(agg @ W1[l] + b1[l]); y written BLOCKED (ksout=KST2)
        k_gemm_mfma<true, true, false, ushort_t>
            <<<NWG1, TB, 0, stream>>>(
                aghi, aglo,
                w1hi + (size_t)l * NT1 * KB1 * 1024, w1lo + (size_t)l * NT1 * KB1 * 1024,
                b1 + (size_t)l * DIM2, yv, nullptr, nullptr,
                N_NODES, DIM2, KST1, KB1, NT1, NWG1, 0, 608, KST2, MT_TILES);
        // GEMM2: h2 = y @ W2[l] + b2[l] + fused per-graph BN stats
        k_gemm_mfma<false, false, true, float>
            <<<NWG2, TB, 0, stream>>>(
                yv, yv,
                w2hi + (size_t)l * NT2 * KB2 * 1024, w2lo + (size_t)l * NT2 * KB2 * 1024,
                b2 + (size_t)l * DIM, h2v, bnsum, bnsq,
                N_NODES, DIM, KST2, KB2, NT2, NWG2, LDA, 304, 0, MT_TILES);
        k_bn_finalize<<<3, 256, 0, stream>>>(bnsum, bnsq, bnmean, bnrstd);
    }
    // final h2 lives in bufB (l=4 even -> pb=bufB)
    k_bn_pool<<<2 * N_GRAPH, TB, 0, stream>>>(
        (const float*)bufB, bat, bat1, bnmean, bnrstd,
        gamma + (size_t)(NLAYER - 1) * DIM, beta + (size_t)(NLAYER - 1) * DIM,
        out_node0, out_node1, pool, out_graph0, out_graph1);
    k_pred<<<cdiv((long long)2 * N_GRAPH * NTASK, TB), TB, 0, stream>>>(
        pool, predW, predb, out_pred0, out_pred1);
}